// Round 3
// baseline (769.795 us; speedup 1.0000x reference)
//
#include <hip/hip_runtime.h>
#include <stdint.h>

// ---------------------------------------------------------------------------
// Threefry-2x32 (20 rounds) — exact JAX semantics.
// Host+device: host side derives kd1/kd2 = split(key(42)) (fold-like,
// jax_threefry_partitionable=True default in modern JAX).
// ---------------------------------------------------------------------------
__host__ __device__ inline void tf2x32(unsigned k0, unsigned k1,
                                       unsigned& x0, unsigned& x1) {
  unsigned k2 = k0 ^ k1 ^ 0x1BD11BDAu;
  x0 += k0; x1 += k1;
#define TFR(r) { x0 += x1; x1 = (x1 << (r)) | (x1 >> (32 - (r))); x1 ^= x0; }
  TFR(13) TFR(15) TFR(26) TFR(6)
  x0 += k1; x1 += k2 + 1u;
  TFR(17) TFR(29) TFR(16) TFR(24)
  x0 += k2; x1 += k0 + 2u;
  TFR(13) TFR(15) TFR(26) TFR(6)
  x0 += k0; x1 += k1 + 3u;
  TFR(17) TFR(29) TFR(16) TFR(24)
  x0 += k1; x1 += k2 + 4u;
  TFR(13) TFR(15) TFR(26) TFR(6)
  x0 += k2; x1 += k0 + 5u;
#undef TFR
}

// Partitionable 32-bit random bits for flat index f: ctr=(0,f), bits = y0^y1.
// uniform = bitcast((bits>>9)|0x3f800000)-1 ; keep iff u < 0.8f.
// Returns the dropout multiplier {0, 1.25}.
__device__ __forceinline__ float drop_scale(unsigned k0, unsigned k1, unsigned f) {
  unsigned a = 0u, b = f;
  tf2x32(k0, k1, a, b);
  unsigned bits = a ^ b;
  float u = __uint_as_float((bits >> 9) | 0x3f800000u) - 1.0f;
  return (u < 0.8f) ? 1.25f : 0.0f;
}

// ---------------------------------------------------------------------------
// CSR build: histogram -> 3-kernel exclusive scan -> cursor fill
// ---------------------------------------------------------------------------
__global__ void count_deg(const int* __restrict__ dst, int* __restrict__ cnt, int e) {
  int i = blockIdx.x * blockDim.x + threadIdx.x;
  if (i < e) atomicAdd(&cnt[dst[i]], 1);
}

__global__ void compute_dinv(const int* __restrict__ cnt, float* __restrict__ dinv, int n) {
  int i = blockIdx.x * blockDim.x + threadIdx.x;
  if (i < n) dinv[i] = 1.0f / sqrtf((float)cnt[i] + 1.0f);  // deg includes self-loop
}

__global__ void scan_local(const int* __restrict__ cnt, int* __restrict__ excl,
                           int* __restrict__ bsum, int n) {
  __shared__ int sh[512];
  int i = blockIdx.x * 512 + threadIdx.x;
  int v = (i < n) ? cnt[i] : 0;
  sh[threadIdx.x] = v;
  __syncthreads();
  for (int d = 1; d < 512; d <<= 1) {
    int t = (threadIdx.x >= d) ? sh[threadIdx.x - d] : 0;
    __syncthreads();
    sh[threadIdx.x] += t;
    __syncthreads();
  }
  if (i < n) excl[i] = sh[threadIdx.x] - v;               // exclusive
  if (threadIdx.x == 511) bsum[blockIdx.x] = sh[511];     // block total
}

__global__ void scan_bsum(int* __restrict__ bsum, int nb) {
  __shared__ int sh[256];
  int tid = threadIdx.x;
  int v = (tid < nb) ? bsum[tid] : 0;
  sh[tid] = v;
  __syncthreads();
  for (int d = 1; d < 256; d <<= 1) {
    int t = (tid >= d) ? sh[tid - d] : 0;
    __syncthreads();
    sh[tid] += t;
    __syncthreads();
  }
  if (tid < nb) bsum[tid] = sh[tid] - v;                  // exclusive
}

__global__ void scan_final(const int* __restrict__ excl, const int* __restrict__ bsum,
                           int* __restrict__ rowptr, int* __restrict__ cursor, int n, int e) {
  int i = blockIdx.x * blockDim.x + threadIdx.x;
  if (i < n) {
    int r = excl[i] + bsum[i >> 9];
    rowptr[i] = r;
    cursor[i] = r;
  }
  if (i == n) rowptr[n] = e;
}

__global__ void fill_adj(const int* __restrict__ src, const int* __restrict__ dst,
                         int* __restrict__ cursor, int* __restrict__ adj, int e) {
  int i = blockIdx.x * blockDim.x + threadIdx.x;
  if (i < e) {
    int d = dst[i];
    int p = atomicAdd(&cursor[d], 1);
    adj[p] = src[i];
  }
}

// ---------------------------------------------------------------------------
// Fused GEMM: Hout[r][c] = dinv[r] * sum_k relu(dropout(A[r][k])) * W[k][c]
// A is [n,128]; W is [128,NOUT] row-major. NCOLP pads cols (NOUT=40 -> 64).
// BM rows/block, 256 threads, 4x4 micro-tile per thread.
// ---------------------------------------------------------------------------
template<int BM, int AP, int NCOLP, int NOUT>
__global__ __launch_bounds__(256) void gemm_drop(
    const float* __restrict__ A, const float* __restrict__ W,
    const float* __restrict__ dinv, float* __restrict__ Hout,
    int n, unsigned kd0, unsigned kd1)
{
  __shared__ float Ash[BM * AP];
  __shared__ float Wsh[128 * NCOLP];
  const int tid = threadIdx.x;
  const int r0 = blockIdx.x * BM;

  // stage W (zero-pad cols >= NOUT)
  if constexpr (NOUT == NCOLP) {
    for (int i = tid; i < 128 * NCOLP / 4; i += 256)
      *(float4*)&Wsh[i * 4] = *(const float4*)&W[i * 4];
  } else {
    for (int i = tid; i < 128 * NCOLP; i += 256) {
      int k = i / NCOLP, c = i % NCOLP;
      Wsh[i] = (c < NOUT) ? W[k * NOUT + c] : 0.0f;
    }
  }

  // stage A with fused dropout(threefry) + relu
  for (int i4 = tid; i4 < BM * 32; i4 += 256) {
    int rr = i4 >> 5;
    int k4 = (i4 & 31) << 2;
    int row = r0 + rr;
    float4 v = make_float4(0.f, 0.f, 0.f, 0.f);
    if (row < n) {
      v = *(const float4*)&A[(size_t)row * 128 + k4];
      unsigned fb = (unsigned)row * 128u + (unsigned)k4;
      float* pv = &v.x;
#pragma unroll
      for (int j = 0; j < 4; ++j)
        pv[j] = fmaxf(pv[j], 0.0f) * drop_scale(kd0, kd1, fb + j);
    }
    *(float4*)&Ash[rr * AP + k4] = v;
  }
  __syncthreads();

  constexpr int CG = NCOLP / 4;          // col groups (32 or 16)
  const int tx = tid % CG, ty = tid / CG;
  const int c0 = tx * 4;
  const int rl = ty * 4;
  float acc[4][4] = {};
  for (int k = 0; k < 128; k += 4) {
    float4 a[4];
#pragma unroll
    for (int i = 0; i < 4; ++i)
      a[i] = *(const float4*)&Ash[(rl + i) * AP + k];
#pragma unroll
    for (int kk = 0; kk < 4; ++kk) {
      float4 w = *(const float4*)&Wsh[(k + kk) * NCOLP + c0];
#pragma unroll
      for (int i = 0; i < 4; ++i) {
        float av = (&a[i].x)[kk];
        acc[i][0] += av * w.x; acc[i][1] += av * w.y;
        acc[i][2] += av * w.z; acc[i][3] += av * w.w;
      }
    }
  }

#pragma unroll
  for (int i = 0; i < 4; ++i) {
    int row = r0 + rl + i;
    if (row < n && (NOUT == NCOLP || c0 < NOUT)) {
      float di = dinv[row];
      float4 o = make_float4(acc[i][0] * di, acc[i][1] * di,
                             acc[i][2] * di, acc[i][3] * di);
      *(float4*)&Hout[(size_t)row * NOUT + c0] = o;
    }
  }
}

// ---------------------------------------------------------------------------
// Pull aggregation (one wave per dst node):
//   out[n][c] = (H[n][c] + sum_{s in adj[n]} H[s][c]) * dinv[n] + bias[c]
// ---------------------------------------------------------------------------
__global__ __launch_bounds__(256) void pull128(
    const float* __restrict__ H, const int* __restrict__ rowptr,
    const int* __restrict__ adj, const float* __restrict__ dinv,
    const float* __restrict__ bias, float* __restrict__ out, int n)
{
  int wid = (blockIdx.x * 256 + threadIdx.x) >> 6;
  int lane = threadIdx.x & 63;
  if (wid >= n) return;
  int beg = rowptr[wid], end = rowptr[wid + 1];
  int c = lane * 2;
  float2 acc = *(const float2*)&H[(size_t)wid * 128 + c];   // self-loop term
  for (int j = beg; j < end; ++j) {
    int s = adj[j];
    float2 v = *(const float2*)&H[(size_t)s * 128 + c];
    acc.x += v.x; acc.y += v.y;
  }
  float di = dinv[wid];
  float2 o;
  o.x = acc.x * di + bias[c];
  o.y = acc.y * di + bias[c + 1];
  *(float2*)&out[(size_t)wid * 128 + c] = o;
}

__global__ __launch_bounds__(256) void pull40(
    const float* __restrict__ H, const int* __restrict__ rowptr,
    const int* __restrict__ adj, const float* __restrict__ dinv,
    const float* __restrict__ bias, float* __restrict__ out, int n)
{
  int wid = (blockIdx.x * 256 + threadIdx.x) >> 6;
  int lane = threadIdx.x & 63;
  if (wid >= n) return;
  int beg = rowptr[wid], end = rowptr[wid + 1];
  float acc = 0.0f;
  if (lane < 40) acc = H[(size_t)wid * 40 + lane];          // self-loop term
  for (int j = beg; j < end; ++j) {
    int s = adj[j];                                         // uniform per wave
    if (lane < 40) acc += H[(size_t)s * 40 + lane];
  }
  if (lane < 40) out[(size_t)wid * 40 + lane] = acc * dinv[wid] + bias[lane];
}

// ---------------------------------------------------------------------------
extern "C" void kernel_launch(void* const* d_in, const int* in_sizes, int n_in,
                              void* d_out, int out_size, void* d_ws, size_t ws_size,
                              hipStream_t stream) {
  const float* x  = (const float*)d_in[0];
  const int*   ei = (const int*)d_in[1];
  const float* W1 = (const float*)d_in[2];
  const float* b1 = (const float*)d_in[3];
  const float* W2 = (const float*)d_in[4];
  const float* b2 = (const float*)d_in[5];
  const int n = in_sizes[0] / 128;
  const int e = in_sizes[1] / 2;
  const int* src = ei;
  const int* dst = ei + e;

  // kd1, kd2 = jax.random.split(jax.random.key(42))  [fold-like split]
  unsigned kd1a = 0u, kd1b = 0u; tf2x32(0u, 42u, kd1a, kd1b);  // ctr (0,0)
  unsigned kd2a = 0u, kd2b = 1u; tf2x32(0u, 42u, kd2a, kd2b);  // ctr (0,1)

  char* wsp = (char*)d_ws;
  size_t off = 0;
  auto take = [&](size_t bytes) -> char* {
    char* p = wsp + off;
    off = (off + bytes + 255) & ~(size_t)255;
    return p;
  };
  int*   cnt    = (int*)take((size_t)n * 4);
  int*   excl   = (int*)take((size_t)n * 4);
  int*   bsum   = (int*)take(1024);
  int*   rowptr = (int*)take((size_t)(n + 1) * 4);
  int*   cursor = (int*)take((size_t)n * 4);
  int*   adj    = (int*)take((size_t)e * 4);
  float* dinv   = (float*)take((size_t)n * 4);
  float* Hbuf   = (float*)take((size_t)n * 128 * 4);
  float* Sbuf   = (float*)take((size_t)n * 128 * 4);
  (void)ws_size; (void)n_in; (void)out_size;

  hipMemsetAsync(cnt, 0, (size_t)n * 4, stream);
  count_deg<<<(e + 255) / 256, 256, 0, stream>>>(dst, cnt, e);
  int nblk = (n + 511) / 512;
  scan_local<<<nblk, 512, 0, stream>>>(cnt, excl, bsum, n);
  scan_bsum<<<1, 256, 0, stream>>>(bsum, nblk);
  scan_final<<<(n + 256) / 256, 256, 0, stream>>>(excl, bsum, rowptr, cursor, n, e);
  compute_dinv<<<(n + 255) / 256, 256, 0, stream>>>(cnt, dinv, n);
  fill_adj<<<(e + 255) / 256, 256, 0, stream>>>(src, dst, cursor, adj, e);

  // layer 1: h1' = dinv * (relu(drop_kd1(x)) @ W1)  ->  s1 = pull(h1') + b1
  gemm_drop<32, 128, 128, 128><<<(n + 31) / 32, 256, 0, stream>>>(
      x, W1, dinv, Hbuf, n, kd1a, kd1b);
  pull128<<<(n + 3) / 4, 256, 0, stream>>>(Hbuf, rowptr, adj, dinv, b1, Sbuf, n);

  // layer 2: h2' = dinv * (relu(drop_kd2(s1)) @ W2) -> out = pull(h2') + b2
  gemm_drop<64, 132, 64, 40><<<(n + 63) / 64, 256, 0, stream>>>(
      Sbuf, W2, dinv, Hbuf, n, kd2a, kd2b);
  pull40<<<(n + 3) / 4, 256, 0, stream>>>(Hbuf, rowptr, adj, dinv, b2,
                                          (float*)d_out, n);
}

// Round 4
// 640.872 us; speedup vs baseline: 1.2012x; 1.2012x over previous
//
#include <hip/hip_runtime.h>
#include <stdint.h>

// ---------------------------------------------------------------------------
// Threefry-2x32 (20 rounds) — exact JAX semantics.
// ---------------------------------------------------------------------------
__host__ __device__ inline void tf2x32(unsigned k0, unsigned k1,
                                       unsigned& x0, unsigned& x1) {
  unsigned k2 = k0 ^ k1 ^ 0x1BD11BDAu;
  x0 += k0; x1 += k1;
#define TFR(r) { x0 += x1; x1 = (x1 << (r)) | (x1 >> (32 - (r))); x1 ^= x0; }
  TFR(13) TFR(15) TFR(26) TFR(6)
  x0 += k1; x1 += k2 + 1u;
  TFR(17) TFR(29) TFR(16) TFR(24)
  x0 += k2; x1 += k0 + 2u;
  TFR(13) TFR(15) TFR(26) TFR(6)
  x0 += k0; x1 += k1 + 3u;
  TFR(17) TFR(29) TFR(16) TFR(24)
  x0 += k1; x1 += k2 + 4u;
  TFR(13) TFR(15) TFR(26) TFR(6)
  x0 += k2; x1 += k0 + 5u;
#undef TFR
}

__device__ __forceinline__ float drop_scale(unsigned k0, unsigned k1, unsigned f) {
  unsigned a = 0u, b = f;
  tf2x32(k0, k1, a, b);
  unsigned bits = a ^ b;
  float u = __uint_as_float((bits >> 9) | 0x3f800000u) - 1.0f;
  return (u < 0.8f) ? 1.25f : 0.0f;
}

// ---------------------------------------------------------------------------
// CSR build: histogram -> 3-kernel exclusive scan -> cursor fill
// ---------------------------------------------------------------------------
__global__ void count_deg(const int* __restrict__ dst, int* __restrict__ cnt, int e) {
  int i = blockIdx.x * blockDim.x + threadIdx.x;
  if (i < e) atomicAdd(&cnt[dst[i]], 1);
}

__global__ void compute_dinv(const int* __restrict__ cnt, float* __restrict__ dinv, int n) {
  int i = blockIdx.x * blockDim.x + threadIdx.x;
  if (i < n) dinv[i] = 1.0f / sqrtf((float)cnt[i] + 1.0f);  // deg includes self-loop
}

__global__ void scan_local(const int* __restrict__ cnt, int* __restrict__ excl,
                           int* __restrict__ bsum, int n) {
  __shared__ int sh[512];
  int i = blockIdx.x * 512 + threadIdx.x;
  int v = (i < n) ? cnt[i] : 0;
  sh[threadIdx.x] = v;
  __syncthreads();
  for (int d = 1; d < 512; d <<= 1) {
    int t = (threadIdx.x >= d) ? sh[threadIdx.x - d] : 0;
    __syncthreads();
    sh[threadIdx.x] += t;
    __syncthreads();
  }
  if (i < n) excl[i] = sh[threadIdx.x] - v;               // exclusive
  if (threadIdx.x == 511) bsum[blockIdx.x] = sh[511];     // block total
}

__global__ void scan_bsum(int* __restrict__ bsum, int nb) {
  __shared__ int sh[256];
  int tid = threadIdx.x;
  int v = (tid < nb) ? bsum[tid] : 0;
  sh[tid] = v;
  __syncthreads();
  for (int d = 1; d < 256; d <<= 1) {
    int t = (tid >= d) ? sh[tid - d] : 0;
    __syncthreads();
    sh[tid] += t;
    __syncthreads();
  }
  if (tid < nb) bsum[tid] = sh[tid] - v;                  // exclusive
}

__global__ void scan_final(const int* __restrict__ excl, const int* __restrict__ bsum,
                           int* __restrict__ rowptr, int* __restrict__ cursor, int n, int e) {
  int i = blockIdx.x * blockDim.x + threadIdx.x;
  if (i < n) {
    int r = excl[i] + bsum[i >> 9];
    rowptr[i] = r;
    cursor[i] = r;
  }
  if (i == n) rowptr[n] = e;
}

__global__ void fill_adj(const int* __restrict__ src, const int* __restrict__ dst,
                         int* __restrict__ cursor, int* __restrict__ adj, int e) {
  int i = blockIdx.x * blockDim.x + threadIdx.x;
  if (i < e) {
    int d = dst[i];
    int p = atomicAdd(&cursor[d], 1);
    adj[p] = src[i];
  }
}

// ---------------------------------------------------------------------------
// Fused GEMM: Hout[r][c] = dinv[r] * sum_k relu(dropout(A[r][k])) * W[k][c]
// ---------------------------------------------------------------------------
template<int BM, int AP, int NCOLP, int NOUT>
__global__ __launch_bounds__(256) void gemm_drop(
    const float* __restrict__ A, const float* __restrict__ W,
    const float* __restrict__ dinv, float* __restrict__ Hout,
    int n, unsigned kd0, unsigned kd1)
{
  __shared__ float Ash[BM * AP];
  __shared__ float Wsh[128 * NCOLP];
  const int tid = threadIdx.x;
  const int r0 = blockIdx.x * BM;

  // stage W (zero-pad cols >= NOUT)
  if constexpr (NOUT == NCOLP) {
    for (int i = tid; i < 128 * NCOLP / 4; i += 256)
      *(float4*)&Wsh[i * 4] = *(const float4*)&W[i * 4];
  } else {
    for (int i = tid; i < 128 * NCOLP; i += 256) {
      int k = i / NCOLP, c = i % NCOLP;
      Wsh[i] = (c < NOUT) ? W[k * NOUT + c] : 0.0f;
    }
  }

  // stage A with fused dropout(threefry) + relu
  for (int i4 = tid; i4 < BM * 32; i4 += 256) {
    int rr = i4 >> 5;
    int k4 = (i4 & 31) << 2;
    int row = r0 + rr;
    float4 v = make_float4(0.f, 0.f, 0.f, 0.f);
    if (row < n) {
      v = *(const float4*)&A[(size_t)row * 128 + k4];
      unsigned fb = (unsigned)row * 128u + (unsigned)k4;
      float* pv = &v.x;
#pragma unroll
      for (int j = 0; j < 4; ++j)
        pv[j] = fmaxf(pv[j], 0.0f) * drop_scale(kd0, kd1, fb + j);
    }
    *(float4*)&Ash[rr * AP + k4] = v;
  }
  __syncthreads();

  constexpr int CG = NCOLP / 4;          // col groups (32 or 16)
  const int tx = tid % CG, ty = tid / CG;
  const int c0 = tx * 4;
  const int rl = ty * 4;
  float acc[4][4] = {};
  for (int k = 0; k < 128; k += 4) {
    float4 a[4];
#pragma unroll
    for (int i = 0; i < 4; ++i)
      a[i] = *(const float4*)&Ash[(rl + i) * AP + k];
#pragma unroll
    for (int kk = 0; kk < 4; ++kk) {
      float4 w = *(const float4*)&Wsh[(k + kk) * NCOLP + c0];
#pragma unroll
      for (int i = 0; i < 4; ++i) {
        float av = (&a[i].x)[kk];
        acc[i][0] += av * w.x; acc[i][1] += av * w.y;
        acc[i][2] += av * w.z; acc[i][3] += av * w.w;
      }
    }
  }

#pragma unroll
  for (int i = 0; i < 4; ++i) {
    int row = r0 + rl + i;
    if (row < n && (NOUT == NCOLP || c0 < NOUT)) {
      float di = dinv[row];
      float4 o = make_float4(acc[i][0] * di, acc[i][1] * di,
                             acc[i][2] * di, acc[i][3] * di);
      *(float4*)&Hout[(size_t)row * NOUT + c0] = o;
    }
  }
}

// ---------------------------------------------------------------------------
// Pull aggregation, latency-pipelined: 8 gathers in flight per wave.
//   out[n][c] = (H[n][c] + sum_{s in adj[n]} H[s][c]) * dinv[n] + bias[c]
// Masked-batch trick: adj index clamped to end-1 (always in-bounds since the
// batch loop only runs when end>beg); masked-off iterations re-gather the
// last row (L1-hit) and are excluded from the accumulate. All conditions are
// wave-uniform.
// ---------------------------------------------------------------------------
__global__ __launch_bounds__(256) void pull128(
    const float* __restrict__ H, const int* __restrict__ rowptr,
    const int* __restrict__ adj, const float* __restrict__ dinv,
    const float* __restrict__ bias, float* __restrict__ out, int n)
{
  int wid = (blockIdx.x * 256 + threadIdx.x) >> 6;
  int lane = threadIdx.x & 63;
  if (wid >= n) return;
  int beg = rowptr[wid], end = rowptr[wid + 1];
  int c = lane * 2;
  const float* Hc = H + c;
  float2 acc[8];
  acc[0] = *(const float2*)&Hc[(size_t)wid * 128];          // self-loop term
#pragma unroll
  for (int k = 1; k < 8; ++k) acc[k] = make_float2(0.f, 0.f);

  int last = end - 1;
  for (int j = beg; j < end; j += 8) {
    int idx[8];
#pragma unroll
    for (int k = 0; k < 8; ++k) idx[k] = adj[min(j + k, last)];
    float2 v[8];
#pragma unroll
    for (int k = 0; k < 8; ++k)
      v[k] = *(const float2*)&Hc[(size_t)idx[k] * 128];
#pragma unroll
    for (int k = 0; k < 8; ++k) {
      if (j + k <= last) { acc[k].x += v[k].x; acc[k].y += v[k].y; }
    }
  }

  float2 s0 = make_float2((acc[0].x + acc[1].x) + (acc[2].x + acc[3].x),
                          (acc[0].y + acc[1].y) + (acc[2].y + acc[3].y));
  float2 s1 = make_float2((acc[4].x + acc[5].x) + (acc[6].x + acc[7].x),
                          (acc[4].y + acc[5].y) + (acc[6].y + acc[7].y));
  float di = dinv[wid];
  float2 o;
  o.x = (s0.x + s1.x) * di + bias[c];
  o.y = (s0.y + s1.y) * di + bias[c + 1];
  *(float2*)&out[(size_t)wid * 128 + c] = o;
}

__global__ __launch_bounds__(256) void pull40(
    const float* __restrict__ H, const int* __restrict__ rowptr,
    const int* __restrict__ adj, const float* __restrict__ dinv,
    const float* __restrict__ bias, float* __restrict__ out, int n)
{
  int wid = (blockIdx.x * 256 + threadIdx.x) >> 6;
  int lane = threadIdx.x & 63;
  if (wid >= n) return;
  int beg = rowptr[wid], end = rowptr[wid + 1];
  bool act = lane < 40;
  float acc[8];
  acc[0] = act ? H[(size_t)wid * 40 + lane] : 0.f;          // self-loop term
#pragma unroll
  for (int k = 1; k < 8; ++k) acc[k] = 0.f;

  int last = end - 1;
  for (int j = beg; j < end; j += 8) {
    int idx[8];
#pragma unroll
    for (int k = 0; k < 8; ++k) idx[k] = adj[min(j + k, last)];
    float v[8];
#pragma unroll
    for (int k = 0; k < 8; ++k)
      v[k] = act ? H[(size_t)idx[k] * 40 + lane] : 0.f;
#pragma unroll
    for (int k = 0; k < 8; ++k) {
      if (j + k <= last) acc[k] += v[k];
    }
  }

  float s = ((acc[0] + acc[1]) + (acc[2] + acc[3])) +
            ((acc[4] + acc[5]) + (acc[6] + acc[7]));
  if (act) out[(size_t)wid * 40 + lane] = s * dinv[wid] + bias[lane];
}

// ---------------------------------------------------------------------------
extern "C" void kernel_launch(void* const* d_in, const int* in_sizes, int n_in,
                              void* d_out, int out_size, void* d_ws, size_t ws_size,
                              hipStream_t stream) {
  const float* x  = (const float*)d_in[0];
  const int*   ei = (const int*)d_in[1];
  const float* W1 = (const float*)d_in[2];
  const float* b1 = (const float*)d_in[3];
  const float* W2 = (const float*)d_in[4];
  const float* b2 = (const float*)d_in[5];
  const int n = in_sizes[0] / 128;
  const int e = in_sizes[1] / 2;
  const int* src = ei;
  const int* dst = ei + e;

  // kd1, kd2 = jax.random.split(jax.random.key(42))  [fold-like split]
  unsigned kd1a = 0u, kd1b = 0u; tf2x32(0u, 42u, kd1a, kd1b);  // ctr (0,0)
  unsigned kd2a = 0u, kd2b = 1u; tf2x32(0u, 42u, kd2a, kd2b);  // ctr (0,1)

  char* wsp = (char*)d_ws;
  size_t off = 0;
  auto take = [&](size_t bytes) -> char* {
    char* p = wsp + off;
    off = (off + bytes + 255) & ~(size_t)255;
    return p;
  };
  int*   cnt    = (int*)take((size_t)n * 4);
  int*   excl   = (int*)take((size_t)n * 4);
  int*   bsum   = (int*)take(1024);
  int*   rowptr = (int*)take((size_t)(n + 1) * 4);
  int*   cursor = (int*)take((size_t)n * 4);
  int*   adj    = (int*)take((size_t)e * 4);
  float* dinv   = (float*)take((size_t)n * 4);
  float* Hbuf   = (float*)take((size_t)n * 128 * 4);
  float* Sbuf   = (float*)take((size_t)n * 128 * 4);
  (void)ws_size; (void)n_in; (void)out_size;

  hipMemsetAsync(cnt, 0, (size_t)n * 4, stream);
  count_deg<<<(e + 255) / 256, 256, 0, stream>>>(dst, cnt, e);
  int nblk = (n + 511) / 512;
  scan_local<<<nblk, 512, 0, stream>>>(cnt, excl, bsum, n);
  scan_bsum<<<1, 256, 0, stream>>>(bsum, nblk);
  scan_final<<<(n + 256) / 256, 256, 0, stream>>>(excl, bsum, rowptr, cursor, n, e);
  compute_dinv<<<(n + 255) / 256, 256, 0, stream>>>(cnt, dinv, n);
  fill_adj<<<(e + 255) / 256, 256, 0, stream>>>(src, dst, cursor, adj, e);

  // layer 1: h1' = dinv * (relu(drop_kd1(x)) @ W1)  ->  s1 = pull(h1') + b1
  gemm_drop<32, 128, 128, 128><<<(n + 31) / 32, 256, 0, stream>>>(
      x, W1, dinv, Hbuf, n, kd1a, kd1b);
  pull128<<<(n + 3) / 4, 256, 0, stream>>>(Hbuf, rowptr, adj, dinv, b1, Sbuf, n);

  // layer 2: h2' = dinv * (relu(drop_kd2(s1)) @ W2) -> out = pull(h2') + b2
  gemm_drop<64, 132, 64, 40><<<(n + 63) / 64, 256, 0, stream>>>(
      Sbuf, W2, dinv, Hbuf, n, kd2a, kd2b);
  pull40<<<(n + 3) / 4, 256, 0, stream>>>(Hbuf, rowptr, adj, dinv, b2,
                                          (float*)d_out, n);
}

// Round 5
// 560.872 us; speedup vs baseline: 1.3725x; 1.1426x over previous
//
#include <hip/hip_runtime.h>
#include <stdint.h>

// ---------------------------------------------------------------------------
// Threefry-2x32 (20 rounds) — exact JAX semantics.
// ---------------------------------------------------------------------------
__host__ __device__ inline void tf2x32(unsigned k0, unsigned k1,
                                       unsigned& x0, unsigned& x1) {
  unsigned k2 = k0 ^ k1 ^ 0x1BD11BDAu;
  x0 += k0; x1 += k1;
#define TFR(r) { x0 += x1; x1 = (x1 << (r)) | (x1 >> (32 - (r))); x1 ^= x0; }
  TFR(13) TFR(15) TFR(26) TFR(6)
  x0 += k1; x1 += k2 + 1u;
  TFR(17) TFR(29) TFR(16) TFR(24)
  x0 += k2; x1 += k0 + 2u;
  TFR(13) TFR(15) TFR(26) TFR(6)
  x0 += k0; x1 += k1 + 3u;
  TFR(17) TFR(29) TFR(16) TFR(24)
  x0 += k1; x1 += k2 + 4u;
  TFR(13) TFR(15) TFR(26) TFR(6)
  x0 += k2; x1 += k0 + 5u;
#undef TFR
}

__device__ __forceinline__ float drop_scale(unsigned k0, unsigned k1, unsigned f) {
  unsigned a = 0u, b = f;
  tf2x32(k0, k1, a, b);
  unsigned bits = a ^ b;
  float u = __uint_as_float((bits >> 9) | 0x3f800000u) - 1.0f;
  return (u < 0.8f) ? 1.25f : 0.0f;
}

// ---------------------------------------------------------------------------
// CSR build: count+rank -> scan -> atomic-free fill
// ---------------------------------------------------------------------------
__global__ __launch_bounds__(256) void count_rank(
    const int* __restrict__ dst, int* __restrict__ cnt,
    int* __restrict__ rank, int e) {
  int i0 = (blockIdx.x * 256 + threadIdx.x) * 4;
  if (i0 + 3 < e) {
    int4 d4 = *(const int4*)&dst[i0];
    int4 r4;
    r4.x = atomicAdd(&cnt[d4.x], 1);
    r4.y = atomicAdd(&cnt[d4.y], 1);
    r4.z = atomicAdd(&cnt[d4.z], 1);
    r4.w = atomicAdd(&cnt[d4.w], 1);
    *(int4*)&rank[i0] = r4;
  } else {
    for (int i = i0; i < e; ++i)
      rank[i] = atomicAdd(&cnt[dst[i]], 1);
  }
}

// legacy fallback path (if ws too small for rank[]): batched cursor fill
__global__ __launch_bounds__(256) void fill_adj_cursor(
    const int* __restrict__ src, const int* __restrict__ dst,
    int* __restrict__ cursor, int* __restrict__ adj, int e) {
  int i0 = (blockIdx.x * 256 + threadIdx.x) * 4;
  for (int i = i0; i < min(i0 + 4, e); ++i) {
    int d = dst[i];
    int p = atomicAdd(&cursor[d], 1);
    adj[p] = src[i];
  }
}

// scan_local also emits dinv (deg includes self-loop)
__global__ void scan_local(const int* __restrict__ cnt, int* __restrict__ excl,
                           int* __restrict__ bsum, float* __restrict__ dinv, int n) {
  __shared__ int sh[512];
  int i = blockIdx.x * 512 + threadIdx.x;
  int v = (i < n) ? cnt[i] : 0;
  if (i < n) dinv[i] = 1.0f / sqrtf((float)v + 1.0f);
  sh[threadIdx.x] = v;
  __syncthreads();
  for (int d = 1; d < 512; d <<= 1) {
    int t = (threadIdx.x >= d) ? sh[threadIdx.x - d] : 0;
    __syncthreads();
    sh[threadIdx.x] += t;
    __syncthreads();
  }
  if (i < n) excl[i] = sh[threadIdx.x] - v;               // exclusive
  if (threadIdx.x == 511) bsum[blockIdx.x] = sh[511];     // block total
}

__global__ void scan_bsum(int* __restrict__ bsum, int nb) {
  __shared__ int sh[256];
  int tid = threadIdx.x;
  int v = (tid < nb) ? bsum[tid] : 0;
  sh[tid] = v;
  __syncthreads();
  for (int d = 1; d < 256; d <<= 1) {
    int t = (tid >= d) ? sh[tid - d] : 0;
    __syncthreads();
    sh[tid] += t;
    __syncthreads();
  }
  if (tid < nb) bsum[tid] = sh[tid] - v;                  // exclusive
}

__global__ void scan_final(const int* __restrict__ excl, const int* __restrict__ bsum,
                           int* __restrict__ rowptr, int* __restrict__ cursor,
                           int n, int e, int write_cursor) {
  int i = blockIdx.x * blockDim.x + threadIdx.x;
  if (i < n) {
    int r = excl[i] + bsum[i >> 9];
    rowptr[i] = r;
    if (write_cursor) cursor[i] = r;
  }
  if (i == n) rowptr[n] = e;
}

// atomic-free CSR fill: adj[rowptr[d] + rank[i]] = src[i], 8 edges/thread
__global__ __launch_bounds__(256) void fill_csr(
    const int* __restrict__ src, const int* __restrict__ dst,
    const int* __restrict__ rank, const int* __restrict__ rowptr,
    int* __restrict__ adj, int e) {
  int i0 = (blockIdx.x * 256 + threadIdx.x) * 8;
  if (i0 + 7 < e) {
    int4 d0 = *(const int4*)&dst[i0];
    int4 d1 = *(const int4*)&dst[i0 + 4];
    int4 r0 = *(const int4*)&rank[i0];
    int4 r1 = *(const int4*)&rank[i0 + 4];
    int4 s0 = *(const int4*)&src[i0];
    int4 s1 = *(const int4*)&src[i0 + 4];
    int p0 = rowptr[d0.x] + r0.x;
    int p1 = rowptr[d0.y] + r0.y;
    int p2 = rowptr[d0.z] + r0.z;
    int p3 = rowptr[d0.w] + r0.w;
    int p4 = rowptr[d1.x] + r1.x;
    int p5 = rowptr[d1.y] + r1.y;
    int p6 = rowptr[d1.z] + r1.z;
    int p7 = rowptr[d1.w] + r1.w;
    adj[p0] = s0.x; adj[p1] = s0.y; adj[p2] = s0.z; adj[p3] = s0.w;
    adj[p4] = s1.x; adj[p5] = s1.y; adj[p6] = s1.z; adj[p7] = s1.w;
  } else {
    for (int i = i0; i < e; ++i)
      adj[rowptr[dst[i]] + rank[i]] = src[i];
  }
}

// ---------------------------------------------------------------------------
// Fused GEMM: Hout[r][c] = dinv[r] * sum_k relu(dropout(A[r][k])) * W[k][c]
// ---------------------------------------------------------------------------
template<int BM, int AP, int NCOLP, int NOUT>
__global__ __launch_bounds__(256) void gemm_drop(
    const float* __restrict__ A, const float* __restrict__ W,
    const float* __restrict__ dinv, float* __restrict__ Hout,
    int n, unsigned kd0, unsigned kd1)
{
  __shared__ float Ash[BM * AP];
  __shared__ float Wsh[128 * NCOLP];
  const int tid = threadIdx.x;
  const int r0 = blockIdx.x * BM;

  // stage W (zero-pad cols >= NOUT)
  if constexpr (NOUT == NCOLP) {
    for (int i = tid; i < 128 * NCOLP / 4; i += 256)
      *(float4*)&Wsh[i * 4] = *(const float4*)&W[i * 4];
  } else {
    for (int i = tid; i < 128 * NCOLP; i += 256) {
      int k = i / NCOLP, c = i % NCOLP;
      Wsh[i] = (c < NOUT) ? W[k * NOUT + c] : 0.0f;
    }
  }

  // stage A with fused dropout(threefry) + relu
  for (int i4 = tid; i4 < BM * 32; i4 += 256) {
    int rr = i4 >> 5;
    int k4 = (i4 & 31) << 2;
    int row = r0 + rr;
    float4 v = make_float4(0.f, 0.f, 0.f, 0.f);
    if (row < n) {
      v = *(const float4*)&A[(size_t)row * 128 + k4];
      unsigned fb = (unsigned)row * 128u + (unsigned)k4;
      float* pv = &v.x;
#pragma unroll
      for (int j = 0; j < 4; ++j)
        pv[j] = fmaxf(pv[j], 0.0f) * drop_scale(kd0, kd1, fb + j);
    }
    *(float4*)&Ash[rr * AP + k4] = v;
  }
  __syncthreads();

  constexpr int CG = NCOLP / 4;          // col groups (32 or 16)
  const int tx = tid % CG, ty = tid / CG;
  const int c0 = tx * 4;
  const int rl = ty * 4;
  float acc[4][4] = {};
  for (int k = 0; k < 128; k += 4) {
    float4 a[4];
#pragma unroll
    for (int i = 0; i < 4; ++i)
      a[i] = *(const float4*)&Ash[(rl + i) * AP + k];
#pragma unroll
    for (int kk = 0; kk < 4; ++kk) {
      float4 w = *(const float4*)&Wsh[(k + kk) * NCOLP + c0];
#pragma unroll
      for (int i = 0; i < 4; ++i) {
        float av = (&a[i].x)[kk];
        acc[i][0] += av * w.x; acc[i][1] += av * w.y;
        acc[i][2] += av * w.z; acc[i][3] += av * w.w;
      }
    }
  }

#pragma unroll
  for (int i = 0; i < 4; ++i) {
    int row = r0 + rl + i;
    if (row < n && (NOUT == NCOLP || c0 < NOUT)) {
      float di = dinv[row];
      float4 o = make_float4(acc[i][0] * di, acc[i][1] * di,
                             acc[i][2] * di, acc[i][3] * di);
      *(float4*)&Hout[(size_t)row * NOUT + c0] = o;
    }
  }
}

// ---------------------------------------------------------------------------
// Pull aggregation, latency-pipelined: 8 gathers in flight per wave.
// ---------------------------------------------------------------------------
__global__ __launch_bounds__(256) void pull128(
    const float* __restrict__ H, const int* __restrict__ rowptr,
    const int* __restrict__ adj, const float* __restrict__ dinv,
    const float* __restrict__ bias, float* __restrict__ out, int n)
{
  int wid = (blockIdx.x * 256 + threadIdx.x) >> 6;
  int lane = threadIdx.x & 63;
  if (wid >= n) return;
  int beg = rowptr[wid], end = rowptr[wid + 1];
  int c = lane * 2;
  const float* Hc = H + c;
  float2 acc[8];
  acc[0] = *(const float2*)&Hc[(size_t)wid * 128];          // self-loop term
#pragma unroll
  for (int k = 1; k < 8; ++k) acc[k] = make_float2(0.f, 0.f);

  int last = end - 1;
  for (int j = beg; j < end; j += 8) {
    int idx[8];
#pragma unroll
    for (int k = 0; k < 8; ++k) idx[k] = adj[min(j + k, last)];
    float2 v[8];
#pragma unroll
    for (int k = 0; k < 8; ++k)
      v[k] = *(const float2*)&Hc[(size_t)idx[k] * 128];
#pragma unroll
    for (int k = 0; k < 8; ++k) {
      if (j + k <= last) { acc[k].x += v[k].x; acc[k].y += v[k].y; }
    }
  }

  float2 s0 = make_float2((acc[0].x + acc[1].x) + (acc[2].x + acc[3].x),
                          (acc[0].y + acc[1].y) + (acc[2].y + acc[3].y));
  float2 s1 = make_float2((acc[4].x + acc[5].x) + (acc[6].x + acc[7].x),
                          (acc[4].y + acc[5].y) + (acc[6].y + acc[7].y));
  float di = dinv[wid];
  float2 o;
  o.x = (s0.x + s1.x) * di + bias[c];
  o.y = (s0.y + s1.y) * di + bias[c + 1];
  *(float2*)&out[(size_t)wid * 128 + c] = o;
}

__global__ __launch_bounds__(256) void pull40(
    const float* __restrict__ H, const int* __restrict__ rowptr,
    const int* __restrict__ adj, const float* __restrict__ dinv,
    const float* __restrict__ bias, float* __restrict__ out, int n)
{
  int wid = (blockIdx.x * 256 + threadIdx.x) >> 6;
  int lane = threadIdx.x & 63;
  if (wid >= n) return;
  int beg = rowptr[wid], end = rowptr[wid + 1];
  bool act = lane < 40;
  float acc[8];
  acc[0] = act ? H[(size_t)wid * 40 + lane] : 0.f;          // self-loop term
#pragma unroll
  for (int k = 1; k < 8; ++k) acc[k] = 0.f;

  int last = end - 1;
  for (int j = beg; j < end; j += 8) {
    int idx[8];
#pragma unroll
    for (int k = 0; k < 8; ++k) idx[k] = adj[min(j + k, last)];
    float v[8];
#pragma unroll
    for (int k = 0; k < 8; ++k)
      v[k] = act ? H[(size_t)idx[k] * 40 + lane] : 0.f;
#pragma unroll
    for (int k = 0; k < 8; ++k) {
      if (j + k <= last) acc[k] += v[k];
    }
  }

  float s = ((acc[0] + acc[1]) + (acc[2] + acc[3])) +
            ((acc[4] + acc[5]) + (acc[6] + acc[7]));
  if (act) out[(size_t)wid * 40 + lane] = s * dinv[wid] + bias[lane];
}

// ---------------------------------------------------------------------------
extern "C" void kernel_launch(void* const* d_in, const int* in_sizes, int n_in,
                              void* d_out, int out_size, void* d_ws, size_t ws_size,
                              hipStream_t stream) {
  const float* x  = (const float*)d_in[0];
  const int*   ei = (const int*)d_in[1];
  const float* W1 = (const float*)d_in[2];
  const float* b1 = (const float*)d_in[3];
  const float* W2 = (const float*)d_in[4];
  const float* b2 = (const float*)d_in[5];
  const int n = in_sizes[0] / 128;
  const int e = in_sizes[1] / 2;
  const int* src = ei;
  const int* dst = ei + e;

  // kd1, kd2 = jax.random.split(jax.random.key(42))  [fold-like split]
  unsigned kd1a = 0u, kd1b = 0u; tf2x32(0u, 42u, kd1a, kd1b);  // ctr (0,0)
  unsigned kd2a = 0u, kd2b = 1u; tf2x32(0u, 42u, kd2a, kd2b);  // ctr (0,1)

  char* wsp = (char*)d_ws;
  size_t off = 0;
  auto take = [&](size_t bytes) -> char* {
    char* p = wsp + off;
    off = (off + bytes + 255) & ~(size_t)255;
    return p;
  };
  int*   cnt    = (int*)take((size_t)n * 4);
  int*   excl   = (int*)take((size_t)n * 4);
  int*   bsum   = (int*)take(1024);
  int*   rowptr = (int*)take((size_t)(n + 1) * 4);
  float* dinv   = (float*)take((size_t)n * 4);
  int*   adj    = (int*)take((size_t)e * 4);
  float* Hbuf   = (float*)take((size_t)n * 128 * 4);
  float* Sbuf   = (float*)take((size_t)n * 128 * 4);
  size_t base_off = off;
  int*   rank   = (int*)take((size_t)e * 4);        // fast path only
  bool use_rank = (off <= ws_size);
  int*   cursor = use_rank ? nullptr : (int*)(wsp + base_off);  // n*4 fits (< e*4)
  (void)n_in; (void)out_size;

  hipMemsetAsync(cnt, 0, (size_t)n * 4, stream);
  if (use_rank) {
    count_rank<<<(e / 4 + 256) / 256, 256, 0, stream>>>(dst, cnt, rank, e);
  } else {
    count_rank<<<(e / 4 + 256) / 256, 256, 0, stream>>>(dst, cnt, cursor, e); // rank discarded later
  }
  int nblk = (n + 511) / 512;
  scan_local<<<nblk, 512, 0, stream>>>(cnt, excl, bsum, dinv, n);
  scan_bsum<<<1, 256, 0, stream>>>(bsum, nblk);
  scan_final<<<(n + 256) / 256, 256, 0, stream>>>(excl, bsum, rowptr, cursor,
                                                  n, e, use_rank ? 0 : 1);
  if (use_rank) {
    fill_csr<<<(e / 8 + 256) / 256, 256, 0, stream>>>(src, dst, rank, rowptr, adj, e);
  } else {
    fill_adj_cursor<<<(e / 4 + 256) / 256, 256, 0, stream>>>(src, dst, cursor, adj, e);
  }

  // layer 1: h1' = dinv * (relu(drop_kd1(x)) @ W1)  ->  s1 = pull(h1') + b1
  gemm_drop<32, 128, 128, 128><<<(n + 31) / 32, 256, 0, stream>>>(
      x, W1, dinv, Hbuf, n, kd1a, kd1b);
  pull128<<<(n + 3) / 4, 256, 0, stream>>>(Hbuf, rowptr, adj, dinv, b1, Sbuf, n);

  // layer 2: h2' = dinv * (relu(drop_kd2(s1)) @ W2) -> out = pull(h2') + b2
  gemm_drop<64, 132, 64, 40><<<(n + 63) / 64, 256, 0, stream>>>(
      Sbuf, W2, dinv, Hbuf, n, kd2a, kd2b);
  pull40<<<(n + 3) / 4, 256, 0, stream>>>(Hbuf, rowptr, adj, dinv, b2,
                                          (float*)d_out, n);
}

// Round 6
// 546.010 us; speedup vs baseline: 1.4099x; 1.0272x over previous
//
#include <hip/hip_runtime.h>
#include <stdint.h>

// ---------------------------------------------------------------------------
// Threefry-2x32 (20 rounds) — exact JAX semantics.
// ---------------------------------------------------------------------------
__host__ __device__ inline void tf2x32(unsigned k0, unsigned k1,
                                       unsigned& x0, unsigned& x1) {
  unsigned k2 = k0 ^ k1 ^ 0x1BD11BDAu;
  x0 += k0; x1 += k1;
#define TFR(r) { x0 += x1; x1 = (x1 << (r)) | (x1 >> (32 - (r))); x1 ^= x0; }
  TFR(13) TFR(15) TFR(26) TFR(6)
  x0 += k1; x1 += k2 + 1u;
  TFR(17) TFR(29) TFR(16) TFR(24)
  x0 += k2; x1 += k0 + 2u;
  TFR(13) TFR(15) TFR(26) TFR(6)
  x0 += k0; x1 += k1 + 3u;
  TFR(17) TFR(29) TFR(16) TFR(24)
  x0 += k1; x1 += k2 + 4u;
  TFR(13) TFR(15) TFR(26) TFR(6)
  x0 += k2; x1 += k0 + 5u;
#undef TFR
}

__device__ __forceinline__ float drop_scale(unsigned k0, unsigned k1, unsigned f) {
  unsigned a = 0u, b = f;
  tf2x32(k0, k1, a, b);
  unsigned bits = a ^ b;
  float u = __uint_as_float((bits >> 9) | 0x3f800000u) - 1.0f;
  return (u < 0.8f) ? 1.25f : 0.0f;
}

// fp32 -> bf16 (round-to-nearest-even), and unpack helpers
__device__ __forceinline__ unsigned f2bf(float x) {
  unsigned u = __float_as_uint(x);
  return (u + 0x7fffu + ((u >> 16) & 1u)) >> 16;
}
__device__ __forceinline__ float bf_lo(unsigned u) {         // even col
  return __uint_as_float(u << 16);
}
__device__ __forceinline__ float bf_hi(unsigned u) {         // odd col
  return __uint_as_float(u & 0xffff0000u);
}

// ---------------------------------------------------------------------------
// CSR build: count+rank -> scan -> atomic-free fill
// ---------------------------------------------------------------------------
__global__ __launch_bounds__(256) void count_rank(
    const int* __restrict__ dst, int* __restrict__ cnt,
    int* __restrict__ rank, int e) {
  int i0 = (blockIdx.x * 256 + threadIdx.x) * 4;
  if (i0 + 3 < e) {
    int4 d4 = *(const int4*)&dst[i0];
    int4 r4;
    r4.x = atomicAdd(&cnt[d4.x], 1);
    r4.y = atomicAdd(&cnt[d4.y], 1);
    r4.z = atomicAdd(&cnt[d4.z], 1);
    r4.w = atomicAdd(&cnt[d4.w], 1);
    *(int4*)&rank[i0] = r4;
  } else {
    for (int i = i0; i < e; ++i)
      rank[i] = atomicAdd(&cnt[dst[i]], 1);
  }
}

// legacy fallback path (if ws too small for rank[]): batched cursor fill
__global__ __launch_bounds__(256) void fill_adj_cursor(
    const int* __restrict__ src, const int* __restrict__ dst,
    int* __restrict__ cursor, int* __restrict__ adj, int e) {
  int i0 = (blockIdx.x * 256 + threadIdx.x) * 4;
  for (int i = i0; i < min(i0 + 4, e); ++i) {
    int d = dst[i];
    int p = atomicAdd(&cursor[d], 1);
    adj[p] = src[i];
  }
}

// scan_local also emits dinv (deg includes self-loop)
__global__ void scan_local(const int* __restrict__ cnt, int* __restrict__ excl,
                           int* __restrict__ bsum, float* __restrict__ dinv, int n) {
  __shared__ int sh[512];
  int i = blockIdx.x * 512 + threadIdx.x;
  int v = (i < n) ? cnt[i] : 0;
  if (i < n) dinv[i] = 1.0f / sqrtf((float)v + 1.0f);
  sh[threadIdx.x] = v;
  __syncthreads();
  for (int d = 1; d < 512; d <<= 1) {
    int t = (threadIdx.x >= d) ? sh[threadIdx.x - d] : 0;
    __syncthreads();
    sh[threadIdx.x] += t;
    __syncthreads();
  }
  if (i < n) excl[i] = sh[threadIdx.x] - v;               // exclusive
  if (threadIdx.x == 511) bsum[blockIdx.x] = sh[511];     // block total
}

__global__ void scan_bsum(int* __restrict__ bsum, int nb) {
  __shared__ int sh[256];
  int tid = threadIdx.x;
  int v = (tid < nb) ? bsum[tid] : 0;
  sh[tid] = v;
  __syncthreads();
  for (int d = 1; d < 256; d <<= 1) {
    int t = (tid >= d) ? sh[tid - d] : 0;
    __syncthreads();
    sh[tid] += t;
    __syncthreads();
  }
  if (tid < nb) bsum[tid] = sh[tid] - v;                  // exclusive
}

__global__ void scan_final(const int* __restrict__ excl, const int* __restrict__ bsum,
                           int* __restrict__ rowptr, int* __restrict__ cursor,
                           int n, int e, int write_cursor) {
  int i = blockIdx.x * blockDim.x + threadIdx.x;
  if (i < n) {
    int r = excl[i] + bsum[i >> 9];
    rowptr[i] = r;
    if (write_cursor) cursor[i] = r;
  }
  if (i == n) rowptr[n] = e;
}

// atomic-free CSR fill: adj[rowptr[d] + rank[i]] = src[i], 8 edges/thread
__global__ __launch_bounds__(256) void fill_csr(
    const int* __restrict__ src, const int* __restrict__ dst,
    const int* __restrict__ rank, const int* __restrict__ rowptr,
    int* __restrict__ adj, int e) {
  int i0 = (blockIdx.x * 256 + threadIdx.x) * 8;
  if (i0 + 7 < e) {
    int4 d0 = *(const int4*)&dst[i0];
    int4 d1 = *(const int4*)&dst[i0 + 4];
    int4 r0 = *(const int4*)&rank[i0];
    int4 r1 = *(const int4*)&rank[i0 + 4];
    int4 s0 = *(const int4*)&src[i0];
    int4 s1 = *(const int4*)&src[i0 + 4];
    int p0 = rowptr[d0.x] + r0.x;
    int p1 = rowptr[d0.y] + r0.y;
    int p2 = rowptr[d0.z] + r0.z;
    int p3 = rowptr[d0.w] + r0.w;
    int p4 = rowptr[d1.x] + r1.x;
    int p5 = rowptr[d1.y] + r1.y;
    int p6 = rowptr[d1.z] + r1.z;
    int p7 = rowptr[d1.w] + r1.w;
    adj[p0] = s0.x; adj[p1] = s0.y; adj[p2] = s0.z; adj[p3] = s0.w;
    adj[p4] = s1.x; adj[p5] = s1.y; adj[p6] = s1.z; adj[p7] = s1.w;
  } else {
    for (int i = i0; i < e; ++i)
      adj[rowptr[dst[i]] + rank[i]] = src[i];
  }
}

// ---------------------------------------------------------------------------
// Fused GEMM: h'[r][c] = dinv[r] * sum_k relu(dropout(A[r][k])) * W[k][c]
// Output written as packed bf16 (RNE) — the pull kernels gather it.
// ---------------------------------------------------------------------------
template<int BM, int AP, int NCOLP, int NOUT>
__global__ __launch_bounds__(256) void gemm_drop(
    const float* __restrict__ A, const float* __restrict__ W,
    const float* __restrict__ dinv, unsigned short* __restrict__ Hout,
    int n, unsigned kd0, unsigned kd1)
{
  __shared__ float Ash[BM * AP];
  __shared__ float Wsh[128 * NCOLP];
  const int tid = threadIdx.x;
  const int r0 = blockIdx.x * BM;

  // stage W (zero-pad cols >= NOUT)
  if constexpr (NOUT == NCOLP) {
    for (int i = tid; i < 128 * NCOLP / 4; i += 256)
      *(float4*)&Wsh[i * 4] = *(const float4*)&W[i * 4];
  } else {
    for (int i = tid; i < 128 * NCOLP; i += 256) {
      int k = i / NCOLP, c = i % NCOLP;
      Wsh[i] = (c < NOUT) ? W[k * NOUT + c] : 0.0f;
    }
  }

  // stage A with fused dropout(threefry) + relu
  for (int i4 = tid; i4 < BM * 32; i4 += 256) {
    int rr = i4 >> 5;
    int k4 = (i4 & 31) << 2;
    int row = r0 + rr;
    float4 v = make_float4(0.f, 0.f, 0.f, 0.f);
    if (row < n) {
      v = *(const float4*)&A[(size_t)row * 128 + k4];
      unsigned fb = (unsigned)row * 128u + (unsigned)k4;
      float* pv = &v.x;
#pragma unroll
      for (int j = 0; j < 4; ++j)
        pv[j] = fmaxf(pv[j], 0.0f) * drop_scale(kd0, kd1, fb + j);
    }
    *(float4*)&Ash[rr * AP + k4] = v;
  }
  __syncthreads();

  constexpr int CG = NCOLP / 4;          // col groups (32 or 16)
  const int tx = tid % CG, ty = tid / CG;
  const int c0 = tx * 4;
  const int rl = ty * 4;
  float acc[4][4] = {};
  for (int k = 0; k < 128; k += 4) {
    float4 a[4];
#pragma unroll
    for (int i = 0; i < 4; ++i)
      a[i] = *(const float4*)&Ash[(rl + i) * AP + k];
#pragma unroll
    for (int kk = 0; kk < 4; ++kk) {
      float4 w = *(const float4*)&Wsh[(k + kk) * NCOLP + c0];
#pragma unroll
      for (int i = 0; i < 4; ++i) {
        float av = (&a[i].x)[kk];
        acc[i][0] += av * w.x; acc[i][1] += av * w.y;
        acc[i][2] += av * w.z; acc[i][3] += av * w.w;
      }
    }
  }

#pragma unroll
  for (int i = 0; i < 4; ++i) {
    int row = r0 + rl + i;
    if (row < n && (NOUT == NCOLP || c0 < NOUT)) {
      float di = dinv[row];
      uint2 p;
      p.x = f2bf(acc[i][0] * di) | (f2bf(acc[i][1] * di) << 16);
      p.y = f2bf(acc[i][2] * di) | (f2bf(acc[i][3] * di) << 16);
      *(uint2*)&Hout[(size_t)row * NOUT + c0] = p;   // 8B-aligned: NOUT,c0 even
    }
  }
}

// ---------------------------------------------------------------------------
// Pull aggregation over bf16 h', fp32 accumulate, 8 gathers in flight.
//   out[n][c] = (h'[n][c] + sum_{s in adj[n]} h'[s][c]) * dinv[n] + bias[c]
// ---------------------------------------------------------------------------
__global__ __launch_bounds__(256) void pull128(
    const unsigned short* __restrict__ H, const int* __restrict__ rowptr,
    const int* __restrict__ adj, const float* __restrict__ dinv,
    const float* __restrict__ bias, float* __restrict__ out, int n)
{
  int wid = (blockIdx.x * 256 + threadIdx.x) >> 6;
  int lane = threadIdx.x & 63;
  if (wid >= n) return;
  int beg = rowptr[wid], end = rowptr[wid + 1];
  const unsigned* Hu = (const unsigned*)H;           // 64 uints per row
  unsigned su = Hu[(size_t)wid * 64 + lane];         // self-loop term
  float2 acc[8];
  acc[0] = make_float2(bf_lo(su), bf_hi(su));
#pragma unroll
  for (int k = 1; k < 8; ++k) acc[k] = make_float2(0.f, 0.f);

  int last = end - 1;
  for (int j = beg; j < end; j += 8) {
    int idx[8];
#pragma unroll
    for (int k = 0; k < 8; ++k) idx[k] = adj[min(j + k, last)];
    unsigned u[8];
#pragma unroll
    for (int k = 0; k < 8; ++k)
      u[k] = Hu[(size_t)idx[k] * 64 + lane];
#pragma unroll
    for (int k = 0; k < 8; ++k) {
      if (j + k <= last) { acc[k].x += bf_lo(u[k]); acc[k].y += bf_hi(u[k]); }
    }
  }

  float2 s0 = make_float2((acc[0].x + acc[1].x) + (acc[2].x + acc[3].x),
                          (acc[0].y + acc[1].y) + (acc[2].y + acc[3].y));
  float2 s1 = make_float2((acc[4].x + acc[5].x) + (acc[6].x + acc[7].x),
                          (acc[4].y + acc[5].y) + (acc[6].y + acc[7].y));
  int c = lane * 2;
  float di = dinv[wid];
  float2 o;
  o.x = (s0.x + s1.x) * di + bias[c];
  o.y = (s0.y + s1.y) * di + bias[c + 1];
  *(float2*)&out[(size_t)wid * 128 + c] = o;
}

__global__ __launch_bounds__(256) void pull40(
    const unsigned short* __restrict__ H, const int* __restrict__ rowptr,
    const int* __restrict__ adj, const float* __restrict__ dinv,
    const float* __restrict__ bias, float* __restrict__ out, int n)
{
  int wid = (blockIdx.x * 256 + threadIdx.x) >> 6;
  int lane = threadIdx.x & 63;
  if (wid >= n) return;
  int beg = rowptr[wid], end = rowptr[wid + 1];
  bool act = lane < 40;
  float acc[8];
  acc[0] = act ? __uint_as_float((unsigned)H[(size_t)wid * 40 + lane] << 16) : 0.f;
#pragma unroll
  for (int k = 1; k < 8; ++k) acc[k] = 0.f;

  int last = end - 1;
  for (int j = beg; j < end; j += 8) {
    int idx[8];
#pragma unroll
    for (int k = 0; k < 8; ++k) idx[k] = adj[min(j + k, last)];
    float v[8];
#pragma unroll
    for (int k = 0; k < 8; ++k)
      v[k] = act ? __uint_as_float((unsigned)H[(size_t)idx[k] * 40 + lane] << 16) : 0.f;
#pragma unroll
    for (int k = 0; k < 8; ++k) {
      if (j + k <= last) acc[k] += v[k];
    }
  }

  float s = ((acc[0] + acc[1]) + (acc[2] + acc[3])) +
            ((acc[4] + acc[5]) + (acc[6] + acc[7]));
  if (act) out[(size_t)wid * 40 + lane] = s * dinv[wid] + bias[lane];
}

// ---------------------------------------------------------------------------
extern "C" void kernel_launch(void* const* d_in, const int* in_sizes, int n_in,
                              void* d_out, int out_size, void* d_ws, size_t ws_size,
                              hipStream_t stream) {
  const float* x  = (const float*)d_in[0];
  const int*   ei = (const int*)d_in[1];
  const float* W1 = (const float*)d_in[2];
  const float* b1 = (const float*)d_in[3];
  const float* W2 = (const float*)d_in[4];
  const float* b2 = (const float*)d_in[5];
  const int n = in_sizes[0] / 128;
  const int e = in_sizes[1] / 2;
  const int* src = ei;
  const int* dst = ei + e;

  // kd1, kd2 = jax.random.split(jax.random.key(42))  [fold-like split]
  unsigned kd1a = 0u, kd1b = 0u; tf2x32(0u, 42u, kd1a, kd1b);  // ctr (0,0)
  unsigned kd2a = 0u, kd2b = 1u; tf2x32(0u, 42u, kd2a, kd2b);  // ctr (0,1)

  char* wsp = (char*)d_ws;
  size_t off = 0;
  auto take = [&](size_t bytes) -> char* {
    char* p = wsp + off;
    off = (off + bytes + 255) & ~(size_t)255;
    return p;
  };
  int*   cnt    = (int*)take((size_t)n * 4);
  int*   excl   = (int*)take((size_t)n * 4);
  int*   bsum   = (int*)take(1024);
  int*   rowptr = (int*)take((size_t)(n + 1) * 4);
  float* dinv   = (float*)take((size_t)n * 4);
  int*   adj    = (int*)take((size_t)e * 4);
  unsigned short* Hb = (unsigned short*)take((size_t)n * 128 * 2);  // bf16 h'
  float* Sbuf   = (float*)take((size_t)n * 128 * 4);
  size_t base_off = off;
  int*   rank   = (int*)take((size_t)e * 4);        // fast path only
  bool use_rank = (off <= ws_size);
  int*   cursor = use_rank ? nullptr : (int*)(wsp + base_off);  // n*4 fits (< e*4)
  (void)n_in; (void)out_size;

  hipMemsetAsync(cnt, 0, (size_t)n * 4, stream);
  if (use_rank) {
    count_rank<<<(e / 4 + 256) / 256, 256, 0, stream>>>(dst, cnt, rank, e);
  } else {
    count_rank<<<(e / 4 + 256) / 256, 256, 0, stream>>>(dst, cnt, cursor, e); // rank discarded later
  }
  int nblk = (n + 511) / 512;
  scan_local<<<nblk, 512, 0, stream>>>(cnt, excl, bsum, dinv, n);
  scan_bsum<<<1, 256, 0, stream>>>(bsum, nblk);
  scan_final<<<(n + 256) / 256, 256, 0, stream>>>(excl, bsum, rowptr, cursor,
                                                  n, e, use_rank ? 0 : 1);
  if (use_rank) {
    fill_csr<<<(e / 8 + 256) / 256, 256, 0, stream>>>(src, dst, rank, rowptr, adj, e);
  } else {
    fill_adj_cursor<<<(e / 4 + 256) / 256, 256, 0, stream>>>(src, dst, cursor, adj, e);
  }

  // layer 1: h1' = dinv * (relu(drop_kd1(x)) @ W1)  [bf16]  ->  s1 = pull + b1
  gemm_drop<32, 128, 128, 128><<<(n + 31) / 32, 256, 0, stream>>>(
      x, W1, dinv, Hb, n, kd1a, kd1b);
  pull128<<<(n + 3) / 4, 256, 0, stream>>>(Hb, rowptr, adj, dinv, b1, Sbuf, n);

  // layer 2: h2' = dinv * (relu(drop_kd2(s1)) @ W2) [bf16]  -> out = pull + b2
  gemm_drop<64, 132, 64, 40><<<(n + 63) / 64, 256, 0, stream>>>(
      Sbuf, W2, dinv, Hb, n, kd2a, kd2b);
  pull40<<<(n + 3) / 4, 256, 0, stream>>>(Hb, rowptr, adj, dinv, b2,
                                          (float*)d_out, n);
}